// Round 1
// baseline (145.397 us; speedup 1.0000x reference)
//
#include <hip/hip_runtime.h>

#define B_ 8
#define S_ 2048
#define D_ 256

typedef _Float16 f16;
typedef f16 f16x2 __attribute__((ext_vector_type(2)));
typedef f16 f16x8 __attribute__((ext_vector_type(8)));
typedef float f32x16 __attribute__((ext_vector_type(16)));
typedef unsigned int u32;
typedef u32 u32x4 __attribute__((ext_vector_type(4)));

typedef const __attribute__((address_space(1))) unsigned int* gptr_t;
typedef __attribute__((address_space(3))) unsigned int* lptr_t;

__device__ __forceinline__ void gload_lds16(const void* g, void* l) {
  __builtin_amdgcn_global_load_lds((gptr_t)(unsigned long long)g,
                                   (lptr_t)(unsigned long long)l, 16, 0, 0);
}

__device__ __forceinline__ u32 packf16(float a, float b) {
  f16x2 t; t[0] = (f16)a; t[1] = (f16)b;
  return __builtin_bit_cast(u32, t);
}

// ---------------- prep: x -> xh (f16), xt (f16 transposed) ----------------
__global__ void prep_x(const float* __restrict__ x, f16* __restrict__ xh,
                       f16* __restrict__ xt) {
  __shared__ f16 tile[64][72];
  const int bid = blockIdx.x;                 // 1024 = 8b * 32st * 4dt
  const int dt = bid & 3, st = (bid >> 2) & 31, b = bid >> 7;
  const int s0 = st * 64, d0 = dt * 64;
  const int t = threadIdx.x;                  // 256
#pragma unroll
  for (int it = 0; it < 4; ++it) {
    int idx = it * 256 + t;
    int i = idx >> 4, j4 = idx & 15;
    size_t off = ((size_t)(b * S_ + s0 + i)) * D_ + d0 + j4 * 4;
    float4 v = *reinterpret_cast<const float4*>(x + off);
    f16 h0 = (f16)v.x, h1 = (f16)v.y, h2 = (f16)v.z, h3 = (f16)v.w;
    f16x2 p0 = {h0, h1}, p1 = {h2, h3};
    uint2 w; w.x = __builtin_bit_cast(u32, p0); w.y = __builtin_bit_cast(u32, p1);
    *reinterpret_cast<uint2*>(xh + off) = w;
    tile[i][j4 * 4 + 0] = h0; tile[i][j4 * 4 + 1] = h1;
    tile[i][j4 * 4 + 2] = h2; tile[i][j4 * 4 + 3] = h3;
  }
  __syncthreads();
#pragma unroll
  for (int it = 0; it < 2; ++it) {
    int idx = it * 256 + t;
    int di = idx >> 3, sc = idx & 7;
    f16x8 ov;
#pragma unroll
    for (int u = 0; u < 8; ++u) ov[u] = tile[sc * 8 + u][di];
    size_t off = ((size_t)(b * D_ + d0 + di)) * S_ + s0 + sc * 8;
    *reinterpret_cast<f16x8*>(xt + off) = ov;
  }
}

// ---------------- prep: W_mean|W_logvar -> Wt[128][256] f16 ----------------
__global__ void prep_w(const float* __restrict__ Wm, const float* __restrict__ Wl,
                       f16* __restrict__ Wt) {
  int idx = blockIdx.x * 256 + threadIdx.x;   // grid 128 -> 32768 = 128j * 256d
  int j = idx >> 8, d = idx & 255;
  float v = (j < 64) ? Wm[d * 64 + j] : Wl[d * 64 + (j - 64)];
  Wt[idx] = (f16)v;
}

// ---------------- flash attention: A_det = softmax(x x^T/16) x -------------
// grid 256: b = blockIdx&7 (XCD-major), qtile = blockIdx>>3 (64 q rows)
// 8 waves: s = w>>2 (q-strip of 32), k = w&3 (kv quarter of 512)
__launch_bounds__(512, 2)
__global__ void attn_kern(const f16* __restrict__ xh, const f16* __restrict__ xt,
                          f16* __restrict__ adet) {
  extern __shared__ char lds[];
  const int tid = threadIdx.x;
  const int lane = tid & 63;
  const int w = tid >> 6;
  const int s = w >> 2;
  const int k = w & 3;
  const int l31 = lane & 31;
  const int hi = lane >> 5;
  const int b = blockIdx.x & 7;
  const int qt = blockIdx.x >> 3;
  const int qb = qt * 64;

  const f16* xb  = xh + (size_t)b * S_ * D_;
  const f16* xtb = xt + (size_t)b * D_ * S_;
  f16* tileK = (f16*)(lds + k * 32768);           // [32][256], XOR-swizzled chunks
  f16* tileV = (f16*)(lds + k * 32768 + 16384);   // [256][32], custom slot layout

  // Q fragments (B-operand): Q[q = qb+32s+l31][d = 16kk + 8hi + 0..7]
  f16x8 qf[16];
  {
    const f16* qrow = xb + (size_t)(qb + 32 * s + l31) * D_;
#pragma unroll
    for (int kk = 0; kk < 16; ++kk)
      qf[kk] = *reinterpret_cast<const f16x8*>(qrow + kk * 16 + hi * 8);
  }

  f32x16 o[8];
#pragma unroll
  for (int i = 0; i < 8; ++i)
#pragma unroll
    for (int j = 0; j < 16; ++j) o[i][j] = 0.0f;

  float m_run = -1e30f, lsum = 0.0f;
  const float SC = 0.0901684723f;  // log2(e)/16

#pragma unroll 1
  for (int step = 0; step < 16; ++step) {
    const int kv0 = k * 512 + step * 32;
    // stage (pre-swizzled global source -> linear LDS dest)
    if (s == 0) {
#pragma unroll
      for (int is = 0; is < 16; ++is) {
        int u = is * 64 + lane;
        int r = u >> 5;
        int c = (u & 31) ^ (r & 7);
        gload_lds16(xb + (size_t)(kv0 + r) * D_ + c * 8, tileK + is * 512);
      }
    } else {
#pragma unroll
      for (int is = 0; is < 16; ++is) {
        int u = is * 64 + lane;
        int d = u >> 2;
        int c = (u & 3) ^ ((d >> 1) & 3);
        gload_lds16(xtb + (size_t)d * S_ + kv0 + c * 8, tileV + is * 512);
      }
    }
    __syncthreads();

    // swapped QK^T: acc[r] = (x_kv . q)/1 at kv = crow(r,hi), q = l31
    f32x16 acc;
#pragma unroll
    for (int j = 0; j < 16; ++j) acc[j] = 0.0f;
#pragma unroll
    for (int kk = 0; kk < 16; ++kk) {
      int c = 2 * kk + hi;
      f16x8 af = *reinterpret_cast<const f16x8*>(tileK + l31 * 256 + ((c ^ (l31 & 7)) * 8));
      acc = __builtin_amdgcn_mfma_f32_32x32x16_f16(af, qf[kk], acc, 0, 0, 0);
    }

    // online softmax (lane-local row q=l31; partner lane^32 holds other 16 kv)
    float tm = -1e30f;
#pragma unroll
    for (int j = 0; j < 16; ++j) { acc[j] *= SC; tm = fmaxf(tm, acc[j]); }
    tm = fmaxf(tm, __shfl_xor(tm, 32));
    float m_new = fmaxf(m_run, tm);
    float rs = exp2f(m_run - m_new);
    float ls = 0.0f;
#pragma unroll
    for (int j = 0; j < 16; ++j) { float p = exp2f(acc[j] - m_new); acc[j] = p; ls += p; }
    ls += __shfl_xor(ls, 32);
    lsum = lsum * rs + ls;
    m_run = m_new;
    if (__any(rs < 1.0f)) {
#pragma unroll
      for (int r = 0; r < 16; ++r) {
        int row = (r & 3) + 8 * (r >> 2) + 4 * hi;
        float f = __shfl(rs, row);
#pragma unroll
        for (int ns = 0; ns < 8; ++ns) o[ns][r] *= f;
      }
    }

    // P -> fp16 A-fragments (pair-pack + cross-half exchange)
    u32x4 pf[2];
#pragma unroll
    for (int c2 = 0; c2 < 2; ++c2) {
      u32 a1 = packf16(acc[8 * c2 + 0], acc[8 * c2 + 1]);
      u32 a2 = packf16(acc[8 * c2 + 2], acc[8 * c2 + 3]);
      u32 b1 = packf16(acc[8 * c2 + 4], acc[8 * c2 + 5]);
      u32 b2 = packf16(acc[8 * c2 + 6], acc[8 * c2 + 7]);
      u32 xa1 = __shfl_xor(a1, 32), xa2 = __shfl_xor(a2, 32);
      u32 xb1 = __shfl_xor(b1, 32), xb2 = __shfl_xor(b2, 32);
      u32x4 f;
      f[0] = hi ? xb1 : a1;
      f[1] = hi ? xb2 : a2;
      f[2] = hi ? b1 : xa1;
      f[3] = hi ? b2 : xa2;
      pf[c2] = f;
    }

    // PV: o[ns] += P(32q x 16kv) * V(16kv x 32d)
#pragma unroll
    for (int ns = 0; ns < 8; ++ns) {
      int dd = l31 + 32 * ns;
#pragma unroll
      for (int c2 = 0; c2 < 2; ++c2) {
        int cc = 2 * c2 + hi;
        int slot = dd * 4 + (cc ^ ((dd >> 1) & 3));
        f16x8 vf = *reinterpret_cast<const f16x8*>(tileV + slot * 8);
        o[ns] = __builtin_amdgcn_mfma_f32_32x32x16_f16(
            __builtin_bit_cast(f16x8, pf[c2]), vf, o[ns], 0, 0, 0);
      }
    }
    __syncthreads();
  }

  // ---- split-KV combine ----
  float* statm = (float*)(lds + 131072);   // [2s][4k][32q]
  float* statl = statm + 256;
  if (hi == 0) {
    statm[(s * 4 + k) * 32 + l31] = m_run;
    statl[(s * 4 + k) * 32 + l31] = lsum;
  }
  __syncthreads();

#pragma unroll 1
  for (int phase = 0; phase < 2; ++phase) {
    if (s == phase) {
      float* zone = (float*)(lds + k * 32768);
#pragma unroll
      for (int r = 0; r < 16; ++r) {
        int row = (r & 3) + 8 * (r >> 2) + 4 * hi;
        float M = statm[(s * 4 + 0) * 32 + row];
        M = fmaxf(M, statm[(s * 4 + 1) * 32 + row]);
        M = fmaxf(M, statm[(s * 4 + 2) * 32 + row]);
        M = fmaxf(M, statm[(s * 4 + 3) * 32 + row]);
        float mk = statm[(s * 4 + k) * 32 + row];
        float f = exp2f(mk - M);
        float* zr = zone + row * 256 + l31;
#pragma unroll
        for (int ns = 0; ns < 8; ++ns) zr[ns * 32] = o[ns][r] * f;
      }
    }
    __syncthreads();
#pragma unroll 1
    for (int it = 0; it < 16; ++it) {
      int idx = it * 512 + tid;
      int row = idx >> 8, col = idx & 255;
      float v0 = ((float*)(lds + 0 * 32768))[row * 256 + col];
      float v1 = ((float*)(lds + 1 * 32768))[row * 256 + col];
      float v2 = ((float*)(lds + 2 * 32768))[row * 256 + col];
      float v3 = ((float*)(lds + 3 * 32768))[row * 256 + col];
      float m0 = statm[(phase * 4 + 0) * 32 + row];
      float m1 = statm[(phase * 4 + 1) * 32 + row];
      float m2 = statm[(phase * 4 + 2) * 32 + row];
      float m3 = statm[(phase * 4 + 3) * 32 + row];
      float M = fmaxf(fmaxf(m0, m1), fmaxf(m2, m3));
      float L = statl[(phase * 4 + 0) * 32 + row] * exp2f(m0 - M)
              + statl[(phase * 4 + 1) * 32 + row] * exp2f(m1 - M)
              + statl[(phase * 4 + 2) * 32 + row] * exp2f(m2 - M)
              + statl[(phase * 4 + 3) * 32 + row] * exp2f(m3 - M);
      float outv = (v0 + v1 + v2 + v3) / L;
      adet[(size_t)(b * S_ + qb + phase * 32 + row) * D_ + col] = (f16)outv;
    }
    __syncthreads();
  }
}

// ------- A_det @ [W_mean|W_logvar] + bias, reparam, write 3 outputs --------
__launch_bounds__(64)
__global__ void gemm2(const f16* __restrict__ adet, const f16* __restrict__ Wt,
                      const float* __restrict__ bm, const float* __restrict__ bl,
                      const float* __restrict__ eps, float* __restrict__ out) {
  const int lane = threadIdx.x & 63;
  const int l31 = lane & 31, hi = lane >> 5;
  const int rb = blockIdx.x * 32;   // grid 512
  f16x8 af[16];
  const f16* arow = adet + (size_t)(rb + l31) * 256;
#pragma unroll
  for (int kk = 0; kk < 16; ++kk)
    af[kk] = *reinterpret_cast<const f16x8*>(arow + kk * 16 + hi * 8);
  f32x16 acc[4];
#pragma unroll
  for (int i = 0; i < 4; ++i)
#pragma unroll
    for (int j = 0; j < 16; ++j) acc[i][j] = 0.0f;
#pragma unroll
  for (int ns = 0; ns < 4; ++ns) {
    const f16* wrow = Wt + (size_t)(l31 + 32 * ns) * 256;
#pragma unroll
    for (int kk = 0; kk < 16; ++kk) {
      f16x8 bf = *reinterpret_cast<const f16x8*>(wrow + kk * 16 + hi * 8);
      acc[ns] = __builtin_amdgcn_mfma_f32_32x32x16_f16(af[kk], bf, acc[ns], 0, 0, 0);
    }
  }
#pragma unroll
  for (int ns = 0; ns < 2; ++ns) {
    int c = l31 + 32 * ns;
    float bmv = bm[c], blv = bl[c];
#pragma unroll
    for (int r = 0; r < 16; ++r) {
      int row = (r & 3) + 8 * (r >> 2) + 4 * hi;
      int grow = rb + row;
      float mean = acc[ns][r] + bmv;
      float lv = acc[ns + 2][r] + blv;
      float e = eps[grow * 64 + c];
      float a = mean + exp2f(0.7213475204f * lv) * e;
      out[grow * 64 + c] = mean;
      out[1048576 + grow * 64 + c] = lv;
      out[2097152 + grow * 64 + c] = a;
    }
  }
}

extern "C" void kernel_launch(void* const* d_in, const int* in_sizes, int n_in,
                              void* d_out, int out_size, void* d_ws, size_t ws_size,
                              hipStream_t stream) {
  (void)in_sizes; (void)n_in; (void)out_size; (void)ws_size;
  const float* x  = (const float*)d_in[0];
  const float* Wm = (const float*)d_in[1];
  const float* bm = (const float*)d_in[2];
  const float* Wl = (const float*)d_in[3];
  const float* bl = (const float*)d_in[4];
  const float* ep = (const float*)d_in[5];
  float* out = (float*)d_out;

  f16* xh   = (f16*)d_ws;                       // 8 MB
  f16* xt   = xh + (size_t)B_ * S_ * D_;        // 8 MB
  f16* adet = xt + (size_t)B_ * S_ * D_;        // 8 MB
  f16* Wt   = adet + (size_t)B_ * S_ * D_;      // 64 KB

  prep_x<<<1024, 256, 0, stream>>>(x, xh, xt);
  prep_w<<<128, 256, 0, stream>>>(Wm, Wl, Wt);
  hipFuncSetAttribute(reinterpret_cast<const void*>(attn_kern),
                      hipFuncAttributeMaxDynamicSharedMemorySize, 133120);
  attn_kern<<<256, 512, 133120, stream>>>(xh, xt, adet);
  gemm2<<<512, 64, 0, stream>>>(adet, Wt, bm, bl, ep, out);
}